// Round 6
// baseline (164.774 us; speedup 1.0000x reference)
//
#include <hip/hip_runtime.h>
#include <cstdint>
#include <cstddef>

#define NTOT 8192
#define KTOT 256

typedef _Float16 half2v __attribute__((ext_vector_type(2)));
typedef _Float16 half8  __attribute__((ext_vector_type(8)));
typedef float floatx16 __attribute__((ext_vector_type(16)));

// ---- workspace layout (bytes) ----
// G_frag: [k32=8][step=260][lane=64][jj=8] f16  (B-operand, fragment layout)
static constexpr size_t G_ELEMS   = (size_t)8 * 260 * 64 * 8;   // 1,064,960 f16
static constexpr size_t OFF_CK    = G_ELEMS * 2;                // 2,129,920
static constexpr size_t OFF_CNT   = OFF_CK + 1024;              // phase-C ticket
static constexpr size_t OFF_BAR   = OFF_CNT + 256;              // grid barrier word
static constexpr size_t OFF_VAL   = 2134016;                    // val2: [8192][4 by][2] f32 = 256 KB

__device__ __forceinline__ uint16_t f2h(float x) {
  _Float16 h = (_Float16)x;
  return __builtin_bit_cast(uint16_t, h);
}

// A-frag: 8 f16 = s2 * rp[0..3]  (4 x v_pk_mul_f16)
__device__ __forceinline__ half8 mkh(half2v s, const half2v* rp) {
  union { half2v p[4]; half8 v; } u;
  u.p[0] = s * rp[0]; u.p[1] = s * rp[1]; u.p[2] = s * rp[2]; u.p[3] = s * rp[3];
  return u.v;
}
__device__ __forceinline__ half8 cph(const half2v* rp) {
  union { half2v p[4]; half8 v; } u;
  u.p[0] = rp[0]; u.p[1] = rp[1]; u.p[2] = rp[2]; u.p[3] = rp[3];
  return u.v;
}

// One-shot grid barrier. bar starts as harness poison 0xAAAAAAAA; the first
// arriving block CASes it to 0. Device-scope atomics (cross-XCD coherent).
// Co-residency of all 256 blocks is guaranteed by the cooperative launch.
__device__ __forceinline__ void grid_barrier(unsigned int* bar) {
  __syncthreads();
  if (threadIdx.x == 0) {
    __threadfence();                                  // release phase-A writes
    atomicCAS(bar, 0xAAAAAAAAu, 0u);                  // poison -> 0 (one winner)
    atomicAdd(bar, 1u);
    while (__hip_atomic_load(bar, __ATOMIC_RELAXED, __HIP_MEMORY_SCOPE_AGENT) < 256u) {
      __builtin_amdgcn_s_sleep(2);
    }
    __threadfence();                                  // acquire others' writes
  }
  __syncthreads();
}

// ---------------- fused: prep -> grid barrier -> GEMM+partial LSE -> last-block reduce
__launch_bounds__(256)
__global__ void fused(const float* __restrict__ x, const float* __restrict__ means,
                      const float* __restrict__ diag, const float* __restrict__ tri,
                      const float* __restrict__ weigh, uint16_t* __restrict__ Gf,
                      float* __restrict__ ck, float* __restrict__ val2,
                      unsigned int* __restrict__ counter, unsigned int* __restrict__ bar,
                      float* __restrict__ out) {
  __shared__ float lv[64], ms[64], bv64[64], wred[256];
  __shared__ float Wp[64][68];   // stride 68: float4-aligned, rotating banks
  __shared__ float SS[64][65];   // stride 65: conflict-free scalar columns
  __shared__ float lse_s;
  __shared__ float xl[128][65];
  __shared__ int ticket_s;

  int t = threadIdx.x;

  // ================= Phase A: per-k prep (k = blockIdx.x) =================
  {
    int k = blockIdx.x;
    if (k == 0 && t == 0) *counter = 0;   // d_ws is re-poisoned each iteration

    // log_softmax denominator over all 256 weights
    float wv = weigh[t];
    wred[t] = wv; __syncthreads();
    for (int o = 128; o > 0; o >>= 1) { if (t < o) wred[t] = fmaxf(wred[t], wred[t + o]); __syncthreads(); }
    float wm = wred[0]; __syncthreads();
    wred[t] = __expf(wv - wm); __syncthreads();
    for (int o = 128; o > 0; o >>= 1) { if (t < o) wred[t] += wred[t + o]; __syncthreads(); }
    if (t == 0) lse_s = wm + __logf(wred[0]);

    float logdet0 = 0.f;   // valid in lane 0 of wave 0 after shuffle
    if (t < 64) {
      float d = diag[k * 64 + t];
      float l = tanhf(d);
      lv[t] = l;
      ms[t] = means[k * 64 + t];
      float ld = __logf(fabsf(l));
      #pragma unroll
      for (int o = 32; o > 0; o >>= 1) ld += __shfl_xor(ld, o);
      logdet0 = ld;
    }
    __syncthreads();

    // build W' = (I + strict_lower(tri)) * diag(lv)
    for (int e = 0; e < 16; ++e) {
      int idx = e * 256 + t;
      int i = idx >> 6, c = idx & 63;
      float L = (c < i) ? tri[k * 4096 + idx] : 0.f;
      float w = ((c == i) ? 1.f : 0.f) + L;
      Wp[i][c] = w * lv[c];
    }
    __syncthreads();

    // S = W'^T W' : each thread a 4x4 tile
    int i0 = (t >> 4) * 4, j0 = (t & 15) * 4;
    float acc[4][4];
    #pragma unroll
    for (int a = 0; a < 4; ++a)
      #pragma unroll
      for (int b = 0; b < 4; ++b) acc[a][b] = 0.f;
    for (int r = 0; r < 64; ++r) {
      float4 av = *(const float4*)&Wp[r][i0];
      float4 bv = *(const float4*)&Wp[r][j0];
      float aa[4] = {av.x, av.y, av.z, av.w};
      float bb[4] = {bv.x, bv.y, bv.z, bv.w};
      #pragma unroll
      for (int a = 0; a < 4; ++a)
        #pragma unroll
        for (int b = 0; b < 4; ++b) acc[a][b] = fmaf(aa[a], bb[b], acc[a][b]);
    }
    #pragma unroll
    for (int a = 0; a < 4; ++a)
      #pragma unroll
      for (int b = 0; b < 4; ++b) SS[i0 + a][j0 + b] = acc[a][b];
    __syncthreads();

    // bv = S m  (conflict-free: SS stride 65), msm via shuffle
    if (t < 64) {
      float b = 0.f;
      for (int j = 0; j < 64; ++j) b = fmaf(SS[t][j], ms[j], b);
      bv64[t] = b;
      float bm = b * ms[t];
      #pragma unroll
      for (int o = 32; o > 0; o >>= 1) bm += __shfl_xor(bm, o);
      if (t == 0) ck[k] = logdet0 + (weigh[k] - lse_s) - 0.5f * bm;
    }
    __syncthreads();

    // Gf stores: 520 x 16B chunks. chunk cc covers features u = 8cc..8cc+7.
    int k32 = k >> 5, kl = k & 31;
    for (int cc = t; cc < 520; cc += 256) {
      float v[8];
      if (cc < 512) {
        int i = cc >> 3, jb = (cc & 7) * 8;
        #pragma unroll
        for (int e = 0; e < 8; ++e) v[e] = -0.5f * SS[i][jb + e];
      } else {
        int b0 = (cc - 512) * 8;
        #pragma unroll
        for (int e = 0; e < 8; ++e) v[e] = bv64[b0 + e];
      }
      uint4 pk;
      pk.x = (uint32_t)f2h(v[0]) | ((uint32_t)f2h(v[1]) << 16);
      pk.y = (uint32_t)f2h(v[2]) | ((uint32_t)f2h(v[3]) << 16);
      pk.z = (uint32_t)f2h(v[4]) | ((uint32_t)f2h(v[5]) << 16);
      pk.w = (uint32_t)f2h(v[6]) | ((uint32_t)f2h(v[7]) << 16);
      size_t base = ((size_t)(k32 * 260 + (cc >> 1)) * 64 + (cc & 1) * 32 + kl) * 8;
      *(uint4*)(Gf + base) = pk;
    }
  }

  // ============ grid-wide barrier (custom, fast) ============
  grid_barrier(bar);

  // ================= Phase B: MFMA GEMM + fused partial LSE ================
  {
    int bx = blockIdx.x >> 2, by = blockIdx.x & 3;  // row-sharing blocks adjacent
    const float* xblk = x + (size_t)bx * (128 * 64);

    for (int e = 0; e < 8; ++e) {
      int lin = e * 1024 + t * 4;
      float4 v = *(const float4*)(xblk + lin);
      int r = lin >> 6, c = lin & 63;
      xl[r][c] = v.x; xl[r][c + 1] = v.y; xl[r][c + 2] = v.z; xl[r][c + 3] = v.w;
    }
    __syncthreads();

    int wave = t >> 6, l = t & 63;
    int wn = wave >> 1, wk = wave & 1;
    int half = l >> 5, lane31 = l & 31;
    int r0 = wn * 64 + lane31, r1 = r0 + 32;

    // per-lane x runs in packed f16: row r, chunks c*16 + half*8 .. +7
    half2v runh0[4][4], runh1[4][4];
    #pragma unroll
    for (int c = 0; c < 4; ++c) {
      int base = c * 16 + half * 8;
      float4 ra = *(const float4*)(xblk + (size_t)r0 * 64 + base);
      float4 rb = *(const float4*)(xblk + (size_t)r0 * 64 + base + 4);
      runh0[c][0][0] = (_Float16)ra.x; runh0[c][0][1] = (_Float16)ra.y;
      runh0[c][1][0] = (_Float16)ra.z; runh0[c][1][1] = (_Float16)ra.w;
      runh0[c][2][0] = (_Float16)rb.x; runh0[c][2][1] = (_Float16)rb.y;
      runh0[c][3][0] = (_Float16)rb.z; runh0[c][3][1] = (_Float16)rb.w;
      float4 rc = *(const float4*)(xblk + (size_t)r1 * 64 + base);
      float4 rd = *(const float4*)(xblk + (size_t)r1 * 64 + base + 4);
      runh1[c][0][0] = (_Float16)rc.x; runh1[c][0][1] = (_Float16)rc.y;
      runh1[c][1][0] = (_Float16)rc.z; runh1[c][1][1] = (_Float16)rc.w;
      runh1[c][2][0] = (_Float16)rd.x; runh1[c][2][1] = (_Float16)rd.y;
      runh1[c][3][0] = (_Float16)rd.z; runh1[c][3][1] = (_Float16)rd.w;
    }

    int k32 = by * 2 + wk;
    const uint4* Bp = (const uint4*)Gf;
    size_t bofs = (size_t)(k32 * 260) * 64 + l;

    floatx16 acc0, acc1;
    #pragma unroll
    for (int i = 0; i < 16; ++i) { acc0[i] = 0.f; acc1[i] = 0.f; }

    // 4-deep prefetch; overruns past step 259 stay inside d_ws (never consumed)
    uint4 bufs[4][4];
    #pragma unroll
    for (int p = 0; p < 4; ++p)
      #pragma unroll
      for (int c = 0; c < 4; ++c) bufs[p][c] = Bp[bofs + (size_t)(p * 4 + c) * 64];

    for (int g = 0; g < 64; g += 4) {
      #pragma unroll
      for (int p = 0; p < 4; ++p) {
        int gg = g + p;
        float xf0 = xl[r0][gg], xf1 = xl[r1][gg];
        _Float16 h0 = (_Float16)xf0; half2v xi0; xi0[0] = h0; xi0[1] = h0;
        _Float16 h1 = (_Float16)xf1; half2v xi1; xi1[0] = h1; xi1[1] = h1;
        #pragma unroll
        for (int c = 0; c < 4; ++c) {
          half8 a0 = mkh(xi0, runh0[c]);
          half8 a1 = mkh(xi1, runh1[c]);
          half8 bb = __builtin_bit_cast(half8, bufs[p][c]);
          acc0 = __builtin_amdgcn_mfma_f32_32x32x16_f16(a0, bb, acc0, 0, 0, 0);
          acc1 = __builtin_amdgcn_mfma_f32_32x32x16_f16(a1, bb, acc1, 0, 0, 0);
        }
        #pragma unroll
        for (int c = 0; c < 4; ++c)
          bufs[p][c] = Bp[bofs + (size_t)((gg + 4) * 4 + c) * 64];
      }
    }

    // tail: steps 256..259 (Sm features, A = raw x) — prefetched in bufs[0]
    #pragma unroll
    for (int c = 0; c < 4; ++c) {
      half8 a0 = cph(runh0[c]);
      half8 a1 = cph(runh1[c]);
      half8 bb = __builtin_bit_cast(half8, bufs[0][c]);
      acc0 = __builtin_amdgcn_mfma_f32_32x32x16_f16(a0, bb, acc0, 0, 0, 0);
      acc1 = __builtin_amdgcn_mfma_f32_32x32x16_f16(a1, bb, acc1, 0, 0, 0);
    }

    // epilogue: stash val (+ck) into xl (reuse), then per-row partial LSE
    __syncthreads();
    float ckv = ck[by * 64 + wk * 32 + lane31];
    #pragma unroll
    for (int reg = 0; reg < 16; ++reg) {
      int row = (reg & 3) + 8 * (reg >> 2) + 4 * half;
      xl[wn * 64 + row][wk * 32 + lane31] = acc0[reg] + ckv;
      xl[wn * 64 + 32 + row][wk * 32 + lane31] = acc1[reg] + ckv;
    }
    __syncthreads();
    if (t < 128) {
      float m = -3.0e38f;
      #pragma unroll
      for (int j = 0; j < 64; ++j) m = fmaxf(m, xl[t][j]);
      float s = 0.f;
      #pragma unroll
      for (int j = 0; j < 64; ++j) s += __expf(xl[t][j] - m);
      size_t n = (size_t)bx * 128 + t;
      val2[n * 8 + by * 2 + 0] = m;
      val2[n * 8 + by * 2 + 1] = s;
    }
    __syncthreads();
  }

  // ============ Phase C: last block combines + writes the scalar ============
  if (t == 0) {
    __threadfence();                       // release val2 writes (device scope)
    ticket_s = (int)atomicAdd(counter, 1u);
  }
  __syncthreads();
  if (ticket_s == 255) {
    __threadfence();                       // acquire all blocks' val2
    float acc = 0.f;
    #pragma unroll 4
    for (int i = 0; i < 32; ++i) {
      size_t n = (size_t)i * 256 + t;
      const float4* p = (const float4*)(val2 + n * 8);
      float4 a = p[0], b = p[1];
      float M = fmaxf(fmaxf(a.x, a.z), fmaxf(b.x, b.z));
      float s = a.y * __expf(a.x - M) + a.w * __expf(a.z - M) +
                b.y * __expf(b.x - M) + b.w * __expf(b.z - M);
      acc += M + __logf(s);
    }
    __syncthreads();
    wred[t] = acc; __syncthreads();
    for (int o = 128; o > 0; o >>= 1) { if (t < o) wred[t] += wred[t + o]; __syncthreads(); }
    if (t == 0) out[0] = 58.8120661251f - wred[0] / 8192.0f;  // 32*log(2pi) - mean(lse)
  }
}

extern "C" void kernel_launch(void* const* d_in, const int* in_sizes, int n_in,
                              void* d_out, int out_size, void* d_ws, size_t ws_size,
                              hipStream_t stream) {
  const float* x     = (const float*)d_in[0];
  const float* means = (const float*)d_in[1];
  const float* diag  = (const float*)d_in[2];
  const float* tri   = (const float*)d_in[3];
  const float* weigh = (const float*)d_in[4];

  char* ws = (char*)d_ws;
  uint16_t* Gf          = (uint16_t*)ws;
  float* ck             = (float*)(ws + OFF_CK);
  unsigned int* counter = (unsigned int*)(ws + OFF_CNT);
  unsigned int* bar     = (unsigned int*)(ws + OFF_BAR);
  float* val2           = (float*)(ws + OFF_VAL);
  float* out            = (float*)d_out;

  void* args[] = { (void*)&x, (void*)&means, (void*)&diag, (void*)&tri, (void*)&weigh,
                   (void*)&Gf, (void*)&ck, (void*)&val2, (void*)&counter, (void*)&bar,
                   (void*)&out };
  hipLaunchCooperativeKernel((void*)fused, dim3(256), dim3(256), args, 0, stream);
}

// Round 7
// 120.142 us; speedup vs baseline: 1.3715x; 1.3715x over previous
//
#include <hip/hip_runtime.h>
#include <cstdint>
#include <cstddef>

#define NTOT 8192
#define KTOT 256

typedef _Float16 half2v __attribute__((ext_vector_type(2)));
typedef _Float16 half8  __attribute__((ext_vector_type(8)));
typedef float floatx16 __attribute__((ext_vector_type(16)));

// ---- workspace layout (bytes) ----
// G_frag: [k32=8][step=260][lane=64][jj=8] f16  (B-operand, fragment layout)
static constexpr size_t G_ELEMS   = (size_t)8 * 260 * 64 * 8;   // 1,064,960 f16
static constexpr size_t OFF_CK    = G_ELEMS * 2;                // 2,129,920
static constexpr size_t OFF_CNT   = OFF_CK + 2048;              // ticket counter
static constexpr size_t OFF_VAL   = 2134016;                    // val2: [8192][4 by][2] f32 = 256 KB

__device__ __forceinline__ uint16_t f2h(float x) {
  _Float16 h = (_Float16)x;
  return __builtin_bit_cast(uint16_t, h);
}

// A-frag: 8 f16 = s2 * rp[0..3]  (4 x v_pk_mul_f16)
__device__ __forceinline__ half8 mkh(half2v s, const half2v* rp) {
  union { half2v p[4]; half8 v; } u;
  u.p[0] = s * rp[0]; u.p[1] = s * rp[1]; u.p[2] = s * rp[2]; u.p[3] = s * rp[3];
  return u.v;
}
__device__ __forceinline__ half8 cph(const half2v* rp) {
  union { half2v p[4]; half8 v; } u;
  u.p[0] = rp[0]; u.p[1] = rp[1]; u.p[2] = rp[2]; u.p[3] = rp[3];
  return u.v;
}

// ---------------- P1: per-k prep (incl. redundant log_softmax). 1 block/k ----
__global__ void p1_prep(const float* __restrict__ means, const float* __restrict__ diag,
                        const float* __restrict__ tri, const float* __restrict__ weigh,
                        uint16_t* __restrict__ Gf, float* __restrict__ ck,
                        unsigned int* __restrict__ counter) {
  int k = blockIdx.x;
  int t = threadIdx.x;
  __shared__ float lv[64], ms[64], bv64[64], wred[256];
  __shared__ float Wp[64][68];   // stride 68: float4-aligned, rotating banks
  __shared__ float SS[64][65];   // stride 65: conflict-free scalar columns
  __shared__ float lse_s;

  if (k == 0 && t == 0) *counter = 0;   // d_ws re-poisoned each iteration

  // log_softmax denominator over all 256 weights
  float wv = weigh[t];
  wred[t] = wv; __syncthreads();
  for (int o = 128; o > 0; o >>= 1) { if (t < o) wred[t] = fmaxf(wred[t], wred[t + o]); __syncthreads(); }
  float wm = wred[0]; __syncthreads();
  wred[t] = __expf(wv - wm); __syncthreads();
  for (int o = 128; o > 0; o >>= 1) { if (t < o) wred[t] += wred[t + o]; __syncthreads(); }
  if (t == 0) lse_s = wm + __logf(wred[0]);

  float logdet0 = 0.f;   // valid in lane 0 of wave 0 after shuffle
  if (t < 64) {
    float d = diag[k * 64 + t];
    float l = tanhf(d);
    lv[t] = l;
    ms[t] = means[k * 64 + t];
    float ld = __logf(fabsf(l));
    #pragma unroll
    for (int o = 32; o > 0; o >>= 1) ld += __shfl_xor(ld, o);
    logdet0 = ld;
  }
  __syncthreads();

  // build W' = (I + strict_lower(tri)) * diag(lv)
  for (int e = 0; e < 16; ++e) {
    int idx = e * 256 + t;
    int i = idx >> 6, c = idx & 63;
    float L = (c < i) ? tri[k * 4096 + idx] : 0.f;
    float w = ((c == i) ? 1.f : 0.f) + L;
    Wp[i][c] = w * lv[c];
  }
  __syncthreads();

  // S = W'^T W' : each thread a 4x4 tile
  int i0 = (t >> 4) * 4, j0 = (t & 15) * 4;
  float acc[4][4];
  #pragma unroll
  for (int a = 0; a < 4; ++a)
    #pragma unroll
    for (int b = 0; b < 4; ++b) acc[a][b] = 0.f;
  for (int r = 0; r < 64; ++r) {
    float4 av = *(const float4*)&Wp[r][i0];
    float4 bv = *(const float4*)&Wp[r][j0];
    float aa[4] = {av.x, av.y, av.z, av.w};
    float bb[4] = {bv.x, bv.y, bv.z, bv.w};
    #pragma unroll
    for (int a = 0; a < 4; ++a)
      #pragma unroll
      for (int b = 0; b < 4; ++b) acc[a][b] = fmaf(aa[a], bb[b], acc[a][b]);
  }
  #pragma unroll
  for (int a = 0; a < 4; ++a)
    #pragma unroll
    for (int b = 0; b < 4; ++b) SS[i0 + a][j0 + b] = acc[a][b];
  __syncthreads();

  // bv = S m  (conflict-free: SS stride 65), msm via shuffle
  if (t < 64) {
    float b = 0.f;
    for (int j = 0; j < 64; ++j) b = fmaf(SS[t][j], ms[j], b);
    bv64[t] = b;
    float bm = b * ms[t];
    #pragma unroll
    for (int o = 32; o > 0; o >>= 1) bm += __shfl_xor(bm, o);
    if (t == 0) ck[k] = logdet0 + (weigh[k] - lse_s) - 0.5f * bm;
  }
  __syncthreads();

  // Gf stores: 520 x 16B chunks. chunk cc covers features u = 8cc..8cc+7.
  int k32 = k >> 5, kl = k & 31;
  for (int cc = t; cc < 520; cc += 256) {
    float v[8];
    if (cc < 512) {
      int i = cc >> 3, jb = (cc & 7) * 8;
      #pragma unroll
      for (int e = 0; e < 8; ++e) v[e] = -0.5f * SS[i][jb + e];
    } else {
      int b0 = (cc - 512) * 8;
      #pragma unroll
      for (int e = 0; e < 8; ++e) v[e] = bv64[b0 + e];
    }
    uint4 pk;
    pk.x = (uint32_t)f2h(v[0]) | ((uint32_t)f2h(v[1]) << 16);
    pk.y = (uint32_t)f2h(v[2]) | ((uint32_t)f2h(v[3]) << 16);
    pk.z = (uint32_t)f2h(v[4]) | ((uint32_t)f2h(v[5]) << 16);
    pk.w = (uint32_t)f2h(v[6]) | ((uint32_t)f2h(v[7]) << 16);
    size_t base = ((size_t)(k32 * 260 + (cc >> 1)) * 64 + (cc & 1) * 32 + kl) * 8;
    *(uint4*)(Gf + base) = pk;
  }
}

// ---------------- K2: MFMA GEMM + fused partial LSE + last-block finale ------
// grid (128, 4): bx = 64-row block, by = 64-col block. 512 blocks = 2/CU,
// 2 waves/SIMD. Wave (wn,wk): 32 rows x 32 cols, one 32x32x16 f16 acc tile.
// K-dim: 260 steps (64 groups of 4 + Sm tail), 4-deep register prefetch.
// Epilogue: val2[n][by] = (m, sumexp) over 64 cols; last block (ticket 511)
// combines all (m,s) pairs and writes the scalar.
__launch_bounds__(256, 2)
__global__ void k2_gemm(const float* __restrict__ x, const uint16_t* __restrict__ Gf,
                        const float* __restrict__ ck, float* __restrict__ val2,
                        unsigned int* __restrict__ counter, float* __restrict__ out) {
  __shared__ float xl[64][65];
  __shared__ float fred[256];
  __shared__ int ticket_s;
  int t = threadIdx.x;
  int bx = blockIdx.x, by = blockIdx.y;
  const float* xblk = x + (size_t)bx * (64 * 64);

  // stage the block's 64 x-rows (16 KB) into LDS for the xi broadcasts
  for (int e = 0; e < 4; ++e) {
    int lin = e * 1024 + t * 4;
    float4 v = *(const float4*)(xblk + lin);
    int r = lin >> 6, c = lin & 63;
    xl[r][c] = v.x; xl[r][c + 1] = v.y; xl[r][c + 2] = v.z; xl[r][c + 3] = v.w;
  }
  __syncthreads();

  int wave = t >> 6, l = t & 63;
  int wn = wave >> 1, wk = wave & 1;
  int half = l >> 5, lane31 = l & 31;
  int lr = wn * 32 + lane31;              // lane's row within block

  // per-lane x run in packed f16: row lr, chunks c*16 + half*8 .. +7
  half2v runh[4][4];
  #pragma unroll
  for (int c = 0; c < 4; ++c) {
    int base = c * 16 + half * 8;
    float4 ra = *(const float4*)(xblk + (size_t)lr * 64 + base);
    float4 rb = *(const float4*)(xblk + (size_t)lr * 64 + base + 4);
    runh[c][0][0] = (_Float16)ra.x; runh[c][0][1] = (_Float16)ra.y;
    runh[c][1][0] = (_Float16)ra.z; runh[c][1][1] = (_Float16)ra.w;
    runh[c][2][0] = (_Float16)rb.x; runh[c][2][1] = (_Float16)rb.y;
    runh[c][3][0] = (_Float16)rb.z; runh[c][3][1] = (_Float16)rb.w;
  }

  int k32 = by * 2 + wk;
  const uint4* Bp = (const uint4*)Gf;
  size_t bofs = (size_t)(k32 * 260) * 64 + l;

  floatx16 acc;
  #pragma unroll
  for (int i = 0; i < 16; ++i) acc[i] = 0.f;

  // 4-deep prefetch; overruns past step 259 stay inside d_ws (never consumed)
  uint4 bufs[4][4];
  #pragma unroll
  for (int p = 0; p < 4; ++p)
    #pragma unroll
    for (int c = 0; c < 4; ++c) bufs[p][c] = Bp[bofs + (size_t)(p * 4 + c) * 64];

  for (int g = 0; g < 64; g += 4) {
    #pragma unroll
    for (int p = 0; p < 4; ++p) {
      int gg = g + p;
      float xf = xl[lr][gg];
      _Float16 h = (_Float16)xf; half2v xi; xi[0] = h; xi[1] = h;
      #pragma unroll
      for (int c = 0; c < 4; ++c) {
        half8 a = mkh(xi, runh[c]);
        half8 bb = __builtin_bit_cast(half8, bufs[p][c]);
        acc = __builtin_amdgcn_mfma_f32_32x32x16_f16(a, bb, acc, 0, 0, 0);
      }
      #pragma unroll
      for (int c = 0; c < 4; ++c)
        bufs[p][c] = Bp[bofs + (size_t)((gg + 4) * 4 + c) * 64];
    }
  }

  // tail: steps 256..259 (Sm features, A = raw x) — prefetched in bufs[0]
  #pragma unroll
  for (int c = 0; c < 4; ++c) {
    half8 a = cph(runh[c]);
    half8 bb = __builtin_bit_cast(half8, bufs[0][c]);
    acc = __builtin_amdgcn_mfma_f32_32x32x16_f16(a, bb, acc, 0, 0, 0);
  }

  // epilogue: stash val (+ck) into xl (reuse), then per-row partial LSE
  __syncthreads();
  float ckv = ck[by * 64 + wk * 32 + lane31];
  #pragma unroll
  for (int reg = 0; reg < 16; ++reg) {
    int rr = (reg & 3) + 8 * (reg >> 2) + 4 * half;   // C: col=lane31, row=rr
    xl[wn * 32 + rr][wk * 32 + lane31] = acc[reg] + ckv;
  }
  __syncthreads();
  if (t < 64) {
    float m = -3.0e38f;
    #pragma unroll
    for (int j = 0; j < 64; ++j) m = fmaxf(m, xl[t][j]);
    float s = 0.f;
    #pragma unroll
    for (int j = 0; j < 64; ++j) s += __expf(xl[t][j] - m);
    size_t n = (size_t)bx * 64 + t;
    val2[n * 8 + by * 2 + 0] = m;
    val2[n * 8 + by * 2 + 1] = s;
  }
  __syncthreads();

  // last-block ticket: block 512 of 512 does the final 256 KB reduction
  if (t == 0) {
    __threadfence();                       // release val2 writes (device scope)
    ticket_s = (int)atomicAdd(counter, 1u);
  }
  __syncthreads();
  if (ticket_s == 511) {
    __threadfence();                       // acquire all blocks' val2
    float acc2 = 0.f;
    #pragma unroll 4
    for (int i = 0; i < 32; ++i) {
      size_t n = (size_t)i * 256 + t;
      const float4* p = (const float4*)(val2 + n * 8);
      float4 a = p[0], b = p[1];
      float M = fmaxf(fmaxf(a.x, a.z), fmaxf(b.x, b.z));
      float s = a.y * __expf(a.x - M) + a.w * __expf(a.z - M) +
                b.y * __expf(b.x - M) + b.w * __expf(b.z - M);
      acc2 += M + __logf(s);
    }
    fred[t] = acc2; __syncthreads();
    for (int o = 128; o > 0; o >>= 1) { if (t < o) fred[t] += fred[t + o]; __syncthreads(); }
    if (t == 0) out[0] = 58.8120661251f - fred[0] / 8192.0f;  // 32*log(2pi) - mean(lse)
  }
}

extern "C" void kernel_launch(void* const* d_in, const int* in_sizes, int n_in,
                              void* d_out, int out_size, void* d_ws, size_t ws_size,
                              hipStream_t stream) {
  const float* x     = (const float*)d_in[0];
  const float* means = (const float*)d_in[1];
  const float* diag  = (const float*)d_in[2];
  const float* tri   = (const float*)d_in[3];
  const float* weigh = (const float*)d_in[4];

  char* ws = (char*)d_ws;
  uint16_t* Gf          = (uint16_t*)ws;
  float* ck             = (float*)(ws + OFF_CK);
  unsigned int* counter = (unsigned int*)(ws + OFF_CNT);
  float* val2           = (float*)(ws + OFF_VAL);
  float* out            = (float*)d_out;

  p1_prep<<<dim3(256), dim3(256), 0, stream>>>(means, diag, tri, weigh, Gf, ck, counter);
  k2_gemm<<<dim3(128, 4), dim3(256), 0, stream>>>(x, Gf, ck, val2, counter, out);
}

// Round 8
// 112.124 us; speedup vs baseline: 1.4696x; 1.0715x over previous
//
#include <hip/hip_runtime.h>
#include <cstdint>
#include <cstddef>

#define NTOT 8192
#define KTOT 256

typedef _Float16 half2v __attribute__((ext_vector_type(2)));
typedef _Float16 half8  __attribute__((ext_vector_type(8)));
typedef float floatx16 __attribute__((ext_vector_type(16)));

// ---- workspace layout (bytes) ----
// G_frag: [k32=8][step=260][lane=64][jj=8] f16  (B-operand, fragment layout)
static constexpr size_t G_ELEMS   = (size_t)8 * 260 * 64 * 8;   // 1,064,960 f16
static constexpr size_t OFF_CK    = G_ELEMS * 2;                // 2,129,920
static constexpr size_t OFF_CNT   = OFF_CK + 2048;              // ticket counter
static constexpr size_t OFF_VAL   = 2134016;                    // val2: [8192][4 by][2] f32 = 256 KB

__device__ __forceinline__ uint16_t f2h(float x) {
  _Float16 h = (_Float16)x;
  return __builtin_bit_cast(uint16_t, h);
}

// A-frag: 8 f16 = s2 * rp[0..3]  (4 x v_pk_mul_f16)
__device__ __forceinline__ half8 mkh(half2v s, const half2v* rp) {
  union { half2v p[4]; half8 v; } u;
  u.p[0] = s * rp[0]; u.p[1] = s * rp[1]; u.p[2] = s * rp[2]; u.p[3] = s * rp[3];
  return u.v;
}
__device__ __forceinline__ half8 cph(const half2v* rp) {
  union { half2v p[4]; half8 v; } u;
  u.p[0] = rp[0]; u.p[1] = rp[1]; u.p[2] = rp[2]; u.p[3] = rp[3];
  return u.v;
}

// ---------------- P1: per-k prep (incl. redundant log_softmax). 1 block/k ----
__global__ void p1_prep(const float* __restrict__ means, const float* __restrict__ diag,
                        const float* __restrict__ tri, const float* __restrict__ weigh,
                        uint16_t* __restrict__ Gf, float* __restrict__ ck,
                        unsigned int* __restrict__ counter) {
  int k = blockIdx.x;
  int t = threadIdx.x;
  __shared__ float lv[64], ms[64], bv64[64], wred[256];
  __shared__ float Wp[64][68];   // stride 68: float4-aligned, rotating banks
  __shared__ float SS[64][65];   // stride 65: conflict-free scalar columns
  __shared__ float lse_s;

  if (k == 0 && t == 0) *counter = 0;   // d_ws re-poisoned each iteration

  // log_softmax denominator over all 256 weights
  float wv = weigh[t];
  wred[t] = wv; __syncthreads();
  for (int o = 128; o > 0; o >>= 1) { if (t < o) wred[t] = fmaxf(wred[t], wred[t + o]); __syncthreads(); }
  float wm = wred[0]; __syncthreads();
  wred[t] = __expf(wv - wm); __syncthreads();
  for (int o = 128; o > 0; o >>= 1) { if (t < o) wred[t] += wred[t + o]; __syncthreads(); }
  if (t == 0) lse_s = wm + __logf(wred[0]);

  float logdet0 = 0.f;   // valid in lane 0 of wave 0 after shuffle
  if (t < 64) {
    float d = diag[k * 64 + t];
    float l = tanhf(d);
    lv[t] = l;
    ms[t] = means[k * 64 + t];
    float ld = __logf(fabsf(l));
    #pragma unroll
    for (int o = 32; o > 0; o >>= 1) ld += __shfl_xor(ld, o);
    logdet0 = ld;
  }
  __syncthreads();

  // build W' = (I + strict_lower(tri)) * diag(lv)
  for (int e = 0; e < 16; ++e) {
    int idx = e * 256 + t;
    int i = idx >> 6, c = idx & 63;
    float L = (c < i) ? tri[k * 4096 + idx] : 0.f;
    float w = ((c == i) ? 1.f : 0.f) + L;
    Wp[i][c] = w * lv[c];
  }
  __syncthreads();

  // S = W'^T W' : each thread a 4x4 tile
  int i0 = (t >> 4) * 4, j0 = (t & 15) * 4;
  float acc[4][4];
  #pragma unroll
  for (int a = 0; a < 4; ++a)
    #pragma unroll
    for (int b = 0; b < 4; ++b) acc[a][b] = 0.f;
  for (int r = 0; r < 64; ++r) {
    float4 av = *(const float4*)&Wp[r][i0];
    float4 bv = *(const float4*)&Wp[r][j0];
    float aa[4] = {av.x, av.y, av.z, av.w};
    float bb[4] = {bv.x, bv.y, bv.z, bv.w};
    #pragma unroll
    for (int a = 0; a < 4; ++a)
      #pragma unroll
      for (int b = 0; b < 4; ++b) acc[a][b] = fmaf(aa[a], bb[b], acc[a][b]);
  }
  #pragma unroll
  for (int a = 0; a < 4; ++a)
    #pragma unroll
    for (int b = 0; b < 4; ++b) SS[i0 + a][j0 + b] = acc[a][b];
  __syncthreads();

  // bv = S m  (conflict-free: SS stride 65), msm via shuffle
  if (t < 64) {
    float b = 0.f;
    for (int j = 0; j < 64; ++j) b = fmaf(SS[t][j], ms[j], b);
    bv64[t] = b;
    float bm = b * ms[t];
    #pragma unroll
    for (int o = 32; o > 0; o >>= 1) bm += __shfl_xor(bm, o);
    if (t == 0) ck[k] = logdet0 + (weigh[k] - lse_s) - 0.5f * bm;
  }
  __syncthreads();

  // Gf stores: 520 x 16B chunks. chunk cc covers features u = 8cc..8cc+7.
  int k32 = k >> 5, kl = k & 31;
  for (int cc = t; cc < 520; cc += 256) {
    float v[8];
    if (cc < 512) {
      int i = cc >> 3, jb = (cc & 7) * 8;
      #pragma unroll
      for (int e = 0; e < 8; ++e) v[e] = -0.5f * SS[i][jb + e];
    } else {
      int b0 = (cc - 512) * 8;
      #pragma unroll
      for (int e = 0; e < 8; ++e) v[e] = bv64[b0 + e];
    }
    uint4 pk;
    pk.x = (uint32_t)f2h(v[0]) | ((uint32_t)f2h(v[1]) << 16);
    pk.y = (uint32_t)f2h(v[2]) | ((uint32_t)f2h(v[3]) << 16);
    pk.z = (uint32_t)f2h(v[4]) | ((uint32_t)f2h(v[5]) << 16);
    pk.w = (uint32_t)f2h(v[6]) | ((uint32_t)f2h(v[7]) << 16);
    size_t base = ((size_t)(k32 * 260 + (cc >> 1)) * 64 + (cc & 1) * 32 + kl) * 8;
    *(uint4*)(Gf + base) = pk;
  }
}

// ---------------- K2: MFMA GEMM, LDS-staged B, fused LSE + last-block finale --
// grid (64, 4): bx = 128-row block, by = 64-col block. 256 blocks, 1/CU.
// 4 waves; wave (wn,wk): 64 rows (2 tiles of 32) x 32 cols (slice wk).
// B is staged global->VGPR->LDS once per block (double-buffered chunks of
// 8 steps x 2 slices = 16 KB), read back via contiguous ds_read_b128.
// This kills the per-wave duplicate VMEM streams that bound round 7 (49 us
// at 13% MFMA / 10% VALU: TA/L1 delivery-bound).
__launch_bounds__(256)
__global__ void k2_gemm(const float* __restrict__ x, const uint16_t* __restrict__ Gf,
                        const float* __restrict__ ck, float* __restrict__ val2,
                        unsigned int* __restrict__ counter, float* __restrict__ out) {
  __shared__ float xl[128][65];                        // 33.3 KB: x rows (reused for epilogue)
  __shared__ __align__(16) uint16_t Bsm[2][2][8][512]; // 32 KB: [buf][slice][step][lane*8]
  __shared__ float fred[256];
  __shared__ int ticket_s;
  int t = threadIdx.x;
  int bx = blockIdx.x, by = blockIdx.y;
  const float* xblk = x + (size_t)bx * (128 * 64);

  int wave = t >> 6, l = t & 63;
  int wn = wave >> 1, wk = wave & 1;
  int half = l >> 5, lane31 = l & 31;
  int r0 = wn * 64 + lane31, r1 = r0 + 32;

  const uint4* Bp = (const uint4*)Gf;
  int sig = wave >> 1;            // slice this wave stages
  int jbase = (wave & 1) * 4;     // 4 step-lines per wave

  // stage x rows into LDS (for the uniform-index xi broadcasts)
  for (int e = 0; e < 8; ++e) {
    int lin = e * 1024 + t * 4;
    float4 v = *(const float4*)(xblk + lin);
    int r = lin >> 6, c = lin & 63;
    xl[r][c] = v.x; xl[r][c + 1] = v.y; xl[r][c + 2] = v.z; xl[r][c + 3] = v.w;
  }

  // per-lane x runs in packed f16: row r, chunks c*16 + half*8 .. +7
  half2v runh0[4][4], runh1[4][4];
  #pragma unroll
  for (int c = 0; c < 4; ++c) {
    int base = c * 16 + half * 8;
    float4 ra = *(const float4*)(xblk + (size_t)r0 * 64 + base);
    float4 rb = *(const float4*)(xblk + (size_t)r0 * 64 + base + 4);
    runh0[c][0][0] = (_Float16)ra.x; runh0[c][0][1] = (_Float16)ra.y;
    runh0[c][1][0] = (_Float16)ra.z; runh0[c][1][1] = (_Float16)ra.w;
    runh0[c][2][0] = (_Float16)rb.x; runh0[c][2][1] = (_Float16)rb.y;
    runh0[c][3][0] = (_Float16)rb.z; runh0[c][3][1] = (_Float16)rb.w;
    float4 rc = *(const float4*)(xblk + (size_t)r1 * 64 + base);
    float4 rd = *(const float4*)(xblk + (size_t)r1 * 64 + base + 4);
    runh1[c][0][0] = (_Float16)rc.x; runh1[c][0][1] = (_Float16)rc.y;
    runh1[c][1][0] = (_Float16)rc.z; runh1[c][1][1] = (_Float16)rc.w;
    runh1[c][2][0] = (_Float16)rd.x; runh1[c][2][1] = (_Float16)rd.y;
    runh1[c][3][0] = (_Float16)rd.z; runh1[c][3][1] = (_Float16)rd.w;
  }

  // stage chunk 0 into buf 0
  #pragma unroll
  for (int i = 0; i < 4; ++i) {
    uint4 v = Bp[((size_t)(by * 2 + sig) * 260 + jbase + i) * 64 + l];
    *(uint4*)&Bsm[0][sig][jbase + i][l * 8] = v;
  }
  __syncthreads();

  floatx16 acc0, acc1;
  #pragma unroll
  for (int i = 0; i < 16; ++i) { acc0[i] = 0.f; acc1[i] = 0.f; }

  // main loop: 32 chunks of 8 steps (steps 0..255). Chunk c: read buf c&1,
  // stage chunk c+1 into buf ~(c&1). Chunk 31 stages steps 256..263 (260..263
  // are junk reads inside d_ws, never consumed).
  for (int c = 0; c < 32; ++c) {
    int cur = c & 1, nxt = cur ^ 1;
    uint4 stg[4];
    int s0n = (c + 1) * 8;
    #pragma unroll
    for (int i = 0; i < 4; ++i)
      stg[i] = Bp[((size_t)(by * 2 + sig) * 260 + s0n + jbase + i) * 64 + l];

    float xa0 = xl[r0][2 * c], xa1 = xl[r0][2 * c + 1];
    float xb0 = xl[r1][2 * c], xb1 = xl[r1][2 * c + 1];
    _Float16 ha0 = (_Float16)xa0; half2v xia0; xia0[0] = ha0; xia0[1] = ha0;
    _Float16 ha1 = (_Float16)xa1; half2v xia1; xia1[0] = ha1; xia1[1] = ha1;
    _Float16 hb0 = (_Float16)xb0; half2v xib0; xib0[0] = hb0; xib0[1] = hb0;
    _Float16 hb1 = (_Float16)xb1; half2v xib1; xib1[0] = hb1; xib1[1] = hb1;

    #pragma unroll
    for (int j = 0; j < 8; ++j) {
      int cc = j & 3;
      half2v xi0 = (j < 4) ? xia0 : xia1;
      half2v xi1 = (j < 4) ? xib0 : xib1;
      half8 bb = __builtin_bit_cast(half8, *(const uint4*)&Bsm[cur][wk][j][l * 8]);
      acc0 = __builtin_amdgcn_mfma_f32_32x32x16_f16(mkh(xi0, runh0[cc]), bb, acc0, 0, 0, 0);
      acc1 = __builtin_amdgcn_mfma_f32_32x32x16_f16(mkh(xi1, runh1[cc]), bb, acc1, 0, 0, 0);
    }

    #pragma unroll
    for (int i = 0; i < 4; ++i)
      *(uint4*)&Bsm[nxt][sig][jbase + i][l * 8] = stg[i];
    __syncthreads();
  }

  // tail: steps 256..259 (Sm features, A = raw x) from buf 0, j = 0..3
  #pragma unroll
  for (int j = 0; j < 4; ++j) {
    half8 bb = __builtin_bit_cast(half8, *(const uint4*)&Bsm[0][wk][j][l * 8]);
    acc0 = __builtin_amdgcn_mfma_f32_32x32x16_f16(cph(runh0[j]), bb, acc0, 0, 0, 0);
    acc1 = __builtin_amdgcn_mfma_f32_32x32x16_f16(cph(runh1[j]), bb, acc1, 0, 0, 0);
  }

  // epilogue: stash val (+ck) into xl (x no longer needed), per-row partial LSE
  float ckv = ck[by * 64 + wk * 32 + lane31];
  #pragma unroll
  for (int reg = 0; reg < 16; ++reg) {
    int rr = (reg & 3) + 8 * (reg >> 2) + 4 * half;   // C: col=lane31, row=rr
    xl[wn * 64 + rr][wk * 32 + lane31] = acc0[reg] + ckv;
    xl[wn * 64 + 32 + rr][wk * 32 + lane31] = acc1[reg] + ckv;
  }
  __syncthreads();
  if (t < 128) {
    float m = -3.0e38f;
    #pragma unroll
    for (int j = 0; j < 64; ++j) m = fmaxf(m, xl[t][j]);
    float s = 0.f;
    #pragma unroll
    for (int j = 0; j < 64; ++j) s += __expf(xl[t][j] - m);
    size_t n = (size_t)bx * 128 + t;
    val2[n * 8 + by * 2 + 0] = m;
    val2[n * 8 + by * 2 + 1] = s;
  }
  __syncthreads();

  // last-block ticket: 256th block does the final 256 KB reduction
  if (t == 0) {
    __threadfence();                       // release val2 writes (device scope)
    ticket_s = (int)atomicAdd(counter, 1u);
  }
  __syncthreads();
  if (ticket_s == 255) {
    __threadfence();                       // acquire all blocks' val2
    float acc2 = 0.f;
    #pragma unroll 4
    for (int i = 0; i < 32; ++i) {
      size_t n = (size_t)i * 256 + t;
      const float4* p = (const float4*)(val2 + n * 8);
      float4 a = p[0], b = p[1];
      float M = fmaxf(fmaxf(a.x, a.z), fmaxf(b.x, b.z));
      float s = a.y * __expf(a.x - M) + a.w * __expf(a.z - M) +
                b.y * __expf(b.x - M) + b.w * __expf(b.z - M);
      acc2 += M + __logf(s);
    }
    fred[t] = acc2; __syncthreads();
    for (int o = 128; o > 0; o >>= 1) { if (t < o) fred[t] += fred[t + o]; __syncthreads(); }
    if (t == 0) out[0] = 58.8120661251f - fred[0] / 8192.0f;  // 32*log(2pi) - mean(lse)
  }
}

extern "C" void kernel_launch(void* const* d_in, const int* in_sizes, int n_in,
                              void* d_out, int out_size, void* d_ws, size_t ws_size,
                              hipStream_t stream) {
  const float* x     = (const float*)d_in[0];
  const float* means = (const float*)d_in[1];
  const float* diag  = (const float*)d_in[2];
  const float* tri   = (const float*)d_in[3];
  const float* weigh = (const float*)d_in[4];

  char* ws = (char*)d_ws;
  uint16_t* Gf          = (uint16_t*)ws;
  float* ck             = (float*)(ws + OFF_CK);
  unsigned int* counter = (unsigned int*)(ws + OFF_CNT);
  float* val2           = (float*)(ws + OFF_VAL);
  float* out            = (float*)d_out;

  p1_prep<<<dim3(256), dim3(256), 0, stream>>>(means, diag, tri, weigh, Gf, ck, counter);
  k2_gemm<<<dim3(64, 4), dim3(256), 0, stream>>>(x, Gf, ck, val2, counter, out);
}

// Round 9
// 111.061 us; speedup vs baseline: 1.4836x; 1.0096x over previous
//
#include <hip/hip_runtime.h>
#include <cstdint>
#include <cstddef>

#define NTOT 8192
#define KTOT 256

typedef _Float16 half2v __attribute__((ext_vector_type(2)));
typedef _Float16 half8  __attribute__((ext_vector_type(8)));
typedef float floatx16 __attribute__((ext_vector_type(16)));

// ---- workspace layout (bytes) ----
// G_frag: [k32=8][step=260][lane=64][jj=8] f16  (B-operand, fragment layout)
static constexpr size_t G_ELEMS   = (size_t)8 * 260 * 64 * 8;   // 1,064,960 f16
static constexpr size_t OFF_CK    = G_ELEMS * 2;                // 2,129,920: 256 f32
static constexpr size_t OFF_CNT   = OFF_CK + 2048;              // 33 u32 tickets
static constexpr size_t OFF_BXS   = OFF_CNT + 512;              // 32 f32 bx partial sums
static constexpr size_t OFF_VAL   = 2134016;                    // val2: [8192][8 by][2] f32 = 512 KB

__device__ __forceinline__ uint16_t f2h(float x) {
  _Float16 h = (_Float16)x;
  return __builtin_bit_cast(uint16_t, h);
}

// A-frag: 8 f16 = s2 * rp[0..3]  (4 x v_pk_mul_f16)
__device__ __forceinline__ half8 mkh(half2v s, const half2v* rp) {
  union { half2v p[4]; half8 v; } u;
  u.p[0] = s * rp[0]; u.p[1] = s * rp[1]; u.p[2] = s * rp[2]; u.p[3] = s * rp[3];
  return u.v;
}
__device__ __forceinline__ half8 cph(const half2v* rp) {
  union { half2v p[4]; half8 v; } u;
  u.p[0] = rp[0]; u.p[1] = rp[1]; u.p[2] = rp[2]; u.p[3] = rp[3];
  return u.v;
}

// ---------------- P1: per-k prep (incl. redundant log_softmax). 1 block/k ----
__global__ void p1_prep(const float* __restrict__ means, const float* __restrict__ diag,
                        const float* __restrict__ tri, const float* __restrict__ weigh,
                        uint16_t* __restrict__ Gf, float* __restrict__ ck,
                        unsigned int* __restrict__ counter) {
  int k = blockIdx.x;
  int t = threadIdx.x;
  __shared__ float lv[64], ms[64], bv64[64], wred[256];
  __shared__ float Wp[64][68];   // stride 68: float4-aligned, rotating banks
  __shared__ float SS[64][65];   // stride 65: conflict-free scalar columns
  __shared__ float lse_s;

  if (k == 0 && t < 33) counter[t] = 0;   // d_ws re-poisoned each iteration

  // log_softmax denominator over all 256 weights
  float wv = weigh[t];
  wred[t] = wv; __syncthreads();
  for (int o = 128; o > 0; o >>= 1) { if (t < o) wred[t] = fmaxf(wred[t], wred[t + o]); __syncthreads(); }
  float wm = wred[0]; __syncthreads();
  wred[t] = __expf(wv - wm); __syncthreads();
  for (int o = 128; o > 0; o >>= 1) { if (t < o) wred[t] += wred[t + o]; __syncthreads(); }
  if (t == 0) lse_s = wm + __logf(wred[0]);

  float logdet0 = 0.f;   // valid in lane 0 of wave 0 after shuffle
  if (t < 64) {
    float d = diag[k * 64 + t];
    float l = tanhf(d);
    lv[t] = l;
    ms[t] = means[k * 64 + t];
    float ld = __logf(fabsf(l));
    #pragma unroll
    for (int o = 32; o > 0; o >>= 1) ld += __shfl_xor(ld, o);
    logdet0 = ld;
  }
  __syncthreads();

  // build W' = (I + strict_lower(tri)) * diag(lv)
  for (int e = 0; e < 16; ++e) {
    int idx = e * 256 + t;
    int i = idx >> 6, c = idx & 63;
    float L = (c < i) ? tri[k * 4096 + idx] : 0.f;
    float w = ((c == i) ? 1.f : 0.f) + L;
    Wp[i][c] = w * lv[c];
  }
  __syncthreads();

  // S = W'^T W' : each thread a 4x4 tile
  int i0 = (t >> 4) * 4, j0 = (t & 15) * 4;
  float acc[4][4];
  #pragma unroll
  for (int a = 0; a < 4; ++a)
    #pragma unroll
    for (int b = 0; b < 4; ++b) acc[a][b] = 0.f;
  for (int r = 0; r < 64; ++r) {
    float4 av = *(const float4*)&Wp[r][i0];
    float4 bv = *(const float4*)&Wp[r][j0];
    float aa[4] = {av.x, av.y, av.z, av.w};
    float bb[4] = {bv.x, bv.y, bv.z, bv.w};
    #pragma unroll
    for (int a = 0; a < 4; ++a)
      #pragma unroll
      for (int b = 0; b < 4; ++b) acc[a][b] = fmaf(aa[a], bb[b], acc[a][b]);
  }
  #pragma unroll
  for (int a = 0; a < 4; ++a)
    #pragma unroll
    for (int b = 0; b < 4; ++b) SS[i0 + a][j0 + b] = acc[a][b];
  __syncthreads();

  // bv = S m  (conflict-free: SS stride 65), msm via shuffle
  if (t < 64) {
    float b = 0.f;
    for (int j = 0; j < 64; ++j) b = fmaf(SS[t][j], ms[j], b);
    bv64[t] = b;
    float bm = b * ms[t];
    #pragma unroll
    for (int o = 32; o > 0; o >>= 1) bm += __shfl_xor(bm, o);
    if (t == 0) ck[k] = logdet0 + (weigh[k] - lse_s) - 0.5f * bm;
  }
  __syncthreads();

  // Gf stores: 520 x 16B chunks. chunk cc covers features u = 8cc..8cc+7.
  int k32 = k >> 5, kl = k & 31;
  for (int cc = t; cc < 520; cc += 256) {
    float v[8];
    if (cc < 512) {
      int i = cc >> 3, jb = (cc & 7) * 8;
      #pragma unroll
      for (int e = 0; e < 8; ++e) v[e] = -0.5f * SS[i][jb + e];
    } else {
      int b0 = (cc - 512) * 8;
      #pragma unroll
      for (int e = 0; e < 8; ++e) v[e] = bv64[b0 + e];
    }
    uint4 pk;
    pk.x = (uint32_t)f2h(v[0]) | ((uint32_t)f2h(v[1]) << 16);
    pk.y = (uint32_t)f2h(v[2]) | ((uint32_t)f2h(v[3]) << 16);
    pk.z = (uint32_t)f2h(v[4]) | ((uint32_t)f2h(v[5]) << 16);
    pk.w = (uint32_t)f2h(v[6]) | ((uint32_t)f2h(v[7]) << 16);
    size_t base = ((size_t)(k32 * 260 + (cc >> 1)) * 64 + (cc & 1) * 32 + kl) * 8;
    *(uint4*)(Gf + base) = pk;
  }
}

// ---------------- K2: MFMA GEMM, 256 rows x 32 cols per block ---------------
// grid (32, 8): bx = 256-row block, by = k32 slice (32 cols). 256 blocks,
// 512 threads = 8 waves = 2 waves/SIMD. Wave w: rows 32w..32w+31, one
// 32x32 acc tile. B slice (266 KB) streamed ONCE per block through LDS
// (double-buffered 16-step chunks, staged 2 lines/wave, issued a full
// chunk ahead of the barrier). Epilogue: shfl-reduce partial LSE ->
// val2[n][by]; per-bx ticket combines 8 slices; final ticket -> scalar.
__launch_bounds__(512)
__global__ void k2_gemm(const float* __restrict__ x, const uint16_t* __restrict__ Gf,
                        const float* __restrict__ ck, float* __restrict__ val2,
                        unsigned int* __restrict__ counter, float* __restrict__ bxsum,
                        float* __restrict__ out) {
  __shared__ float xl[256][65];                        // 66.6 KB x rows (f32)
  __shared__ __align__(16) uint16_t Bsm[2][16][512];   // 32 KB double-buffered B
  __shared__ float red[256];
  __shared__ int ticket_s, ticket2_s;

  int t = threadIdx.x;
  int bx = blockIdx.x, by = blockIdx.y;
  const float* xblk = x + (size_t)bx * (256 * 64);
  int w = t >> 6, l = t & 63, half = l >> 5, lane31 = l & 31;
  int r = 32 * w + lane31;      // this lane's row (A row m = lane31 of its tile)

  // stage x rows into LDS (f32, stride 65: conflict-free scalar columns)
  for (int e = 0; e < 8; ++e) {
    int lin = e * 2048 + t * 4;
    float4 v = *(const float4*)(xblk + lin);
    int rr = lin >> 6, c = lin & 63;
    xl[rr][c] = v.x; xl[rr][c + 1] = v.y; xl[rr][c + 2] = v.z; xl[rr][c + 3] = v.w;
  }

  // per-lane x run in packed f16: row r, chunks c*16 + half*8 .. +7
  half2v runh[4][4];
  #pragma unroll
  for (int c = 0; c < 4; ++c) {
    int base = c * 16 + half * 8;
    float4 ra = *(const float4*)(xblk + (size_t)r * 64 + base);
    float4 rb = *(const float4*)(xblk + (size_t)r * 64 + base + 4);
    runh[c][0][0] = (_Float16)ra.x; runh[c][0][1] = (_Float16)ra.y;
    runh[c][1][0] = (_Float16)ra.z; runh[c][1][1] = (_Float16)ra.w;
    runh[c][2][0] = (_Float16)rb.x; runh[c][2][1] = (_Float16)rb.y;
    runh[c][3][0] = (_Float16)rb.z; runh[c][3][1] = (_Float16)rb.w;
  }

  const uint4* Bp = (const uint4*)Gf;
  size_t sb = (size_t)by * 260;

  // stage chunk 0: wave w stages lines 2w, 2w+1
  {
    uint4 s0 = Bp[(sb + 2 * w) * 64 + l];
    uint4 s1 = Bp[(sb + 2 * w + 1) * 64 + l];
    *(uint4*)&Bsm[0][2 * w][l * 8] = s0;
    *(uint4*)&Bsm[0][2 * w + 1][l * 8] = s1;
  }
  __syncthreads();

  floatx16 acc;
  #pragma unroll
  for (int i = 0; i < 16; ++i) acc[i] = 0.f;

  for (int c = 0; c < 16; ++c) {
    int cur = c & 1, nxt = cur ^ 1;
    // issue next chunk's loads first (c==15: tail lines 256..259, waves 0..3)
    uint4 s0, s1;
    bool last = (c == 15);
    if (!last) {
      s0 = Bp[(sb + (c + 1) * 16 + 2 * w) * 64 + l];
      s1 = Bp[(sb + (c + 1) * 16 + 2 * w + 1) * 64 + l];
    } else if (w < 4) {
      s0 = Bp[(sb + 256 + w) * 64 + l];
    }
    __builtin_amdgcn_sched_barrier(0);   // keep loads above the consume body

    // xi broadcasts for feature groups 4c..4c+3
    float xg0 = xl[r][4 * c], xg1 = xl[r][4 * c + 1];
    float xg2 = xl[r][4 * c + 2], xg3 = xl[r][4 * c + 3];
    half2v xi[4];
    { _Float16 h = (_Float16)xg0; xi[0][0] = h; xi[0][1] = h; }
    { _Float16 h = (_Float16)xg1; xi[1][0] = h; xi[1][1] = h; }
    { _Float16 h = (_Float16)xg2; xi[2][0] = h; xi[2][1] = h; }
    { _Float16 h = (_Float16)xg3; xi[3][0] = h; xi[3][1] = h; }

    #pragma unroll
    for (int s = 0; s < 16; ++s) {
      half8 bb = __builtin_bit_cast(half8, *(const uint4*)&Bsm[cur][s][l * 8]);
      acc = __builtin_amdgcn_mfma_f32_32x32x16_f16(mkh(xi[s >> 2], runh[s & 3]), bb, acc, 0, 0, 0);
    }

    if (!last) {
      *(uint4*)&Bsm[nxt][2 * w][l * 8] = s0;
      *(uint4*)&Bsm[nxt][2 * w + 1][l * 8] = s1;
    } else if (w < 4) {
      *(uint4*)&Bsm[nxt][w][l * 8] = s0;
    }
    __syncthreads();
  }

  // tail: steps 256..259 (Sm features, A = raw x) in Bsm[0][0..3]
  #pragma unroll
  for (int s = 0; s < 4; ++s) {
    half8 bb = __builtin_bit_cast(half8, *(const uint4*)&Bsm[0][s][l * 8]);
    acc = __builtin_amdgcn_mfma_f32_32x32x16_f16(cph(runh[s]), bb, acc, 0, 0, 0);
  }

  // epilogue: per-row (m, sumexp) over this block's 32 cols via shfl reduce.
  // C layout: col = lane31, row = (reg&3) + 8*(reg>>2) + 4*half (+ 32w).
  float ckv = ck[by * 32 + lane31];
  float Mv[16], Sv[16];
  #pragma unroll
  for (int reg = 0; reg < 16; ++reg) {
    float v = acc[reg] + ckv;
    float M = v;
    #pragma unroll
    for (int o = 16; o > 0; o >>= 1) M = fmaxf(M, __shfl_xor(M, o));
    float e = __expf(v - M);
    #pragma unroll
    for (int o = 16; o > 0; o >>= 1) e += __shfl_xor(e, o);
    Mv[reg] = M; Sv[reg] = e;
  }
  if (lane31 == 0) {
    #pragma unroll
    for (int reg = 0; reg < 16; ++reg) {
      int rr = (reg & 3) + 8 * (reg >> 2) + 4 * half;
      float2 p; p.x = Mv[reg]; p.y = Sv[reg];
      *(float2*)&val2[((size_t)bx * 256 + 32 * w + rr) * 16 + by * 2] = p;
    }
  }

  // per-bx ticket: 8th block for this bx combines its 256 rows
  if (t == 0) {
    __threadfence();
    ticket_s = (int)atomicAdd(&counter[bx], 1u);
  }
  __syncthreads();
  if (ticket_s == 7) {
    __threadfence();
    float lse = 0.f;
    if (t < 256) {
      const float4* p = (const float4*)&val2[((size_t)bx * 256 + t) * 16];
      float4 a = p[0], b = p[1], c2 = p[2], d = p[3];
      float M = fmaxf(fmaxf(fmaxf(a.x, a.z), fmaxf(b.x, b.z)),
                      fmaxf(fmaxf(c2.x, c2.z), fmaxf(d.x, d.z)));
      float s = a.y * __expf(a.x - M) + a.w * __expf(a.z - M) +
                b.y * __expf(b.x - M) + b.w * __expf(b.z - M) +
                c2.y * __expf(c2.x - M) + c2.w * __expf(c2.z - M) +
                d.y * __expf(d.x - M) + d.w * __expf(d.z - M);
      lse = M + __logf(s);
    }
    if (t < 256) red[t] = lse;
    __syncthreads();
    for (int o = 128; o > 0; o >>= 1) {
      if (t < o) red[t] += red[t + o];
      __syncthreads();
    }
    if (t == 0) {
      bxsum[bx] = red[0];
      __threadfence();
      ticket2_s = (int)atomicAdd(&counter[32], 1u);
    }
    __syncthreads();
    if (ticket2_s == 31 && t == 0) {
      __threadfence();
      float ssum = 0.f;
      for (int i = 0; i < 32; ++i) ssum += bxsum[i];
      out[0] = 58.8120661251f - ssum / 8192.0f;   // 32*log(2pi) - mean(lse)
    }
  }
}

extern "C" void kernel_launch(void* const* d_in, const int* in_sizes, int n_in,
                              void* d_out, int out_size, void* d_ws, size_t ws_size,
                              hipStream_t stream) {
  const float* x     = (const float*)d_in[0];
  const float* means = (const float*)d_in[1];
  const float* diag  = (const float*)d_in[2];
  const float* tri   = (const float*)d_in[3];
  const float* weigh = (const float*)d_in[4];

  char* ws = (char*)d_ws;
  uint16_t* Gf          = (uint16_t*)ws;
  float* ck             = (float*)(ws + OFF_CK);
  unsigned int* counter = (unsigned int*)(ws + OFF_CNT);
  float* bxsum          = (float*)(ws + OFF_BXS);
  float* val2           = (float*)(ws + OFF_VAL);
  float* out            = (float*)d_out;

  p1_prep<<<dim3(256), dim3(256), 0, stream>>>(means, diag, tri, weigh, Gf, ck, counter);
  k2_gemm<<<dim3(32, 8), dim3(512), 0, stream>>>(x, Gf, ck, val2, counter, bxsum, out);
}